// Round 11
// baseline (100.392 us; speedup 1.0000x reference)
//
#include <hip/hip_runtime.h>
#include <hip/hip_bf16.h>
#include <math.h>

// GAT layer B=8, N=2048, F=64 on gfx950.
// Round 11: k_attn rebuilt in the hipBLASLt corner: LOW occupancy
// (2 blocks/CU, 2 waves/SIMD) + BIG VGPR budget (launch_bounds(256,2) ->
// 256 cap) + 4-chunk rolling register prefetch (8 dwordx4 in flight).
// R3/R5/R8/R10 all recreated the same disease: high-occupancy VGPR caps
// (<=128) forced the allocator to serialize B-frag loads, exposing full
// L2/L3 latency per tile (VALUBusy ~22%). Wave = j-quarter (32 x 16-j
// chunks); P register-resident (A[m=lane&31][k=(lane>>5)*8+e], R10-verified);
// 32x32x16 MFMA; psum via 2 rotating accumulators + intra-8 tree.

#define NN 2048
#define BB 8

typedef __attribute__((ext_vector_type(8))) short s8v;     // 8 bf16
typedef __attribute__((ext_vector_type(4))) float f4v;
typedef __attribute__((ext_vector_type(16))) float f16v;   // 32x32 acc
typedef __attribute__((ext_vector_type(4))) unsigned u4v;
typedef __attribute__((ext_vector_type(2))) unsigned long long u64v2;

static __device__ __forceinline__ unsigned pk_bf16(float lo, float hi) {
  __hip_bfloat162 t = __float22bfloat162_rn(float2{lo, hi});
  return *(unsigned*)&t;
}
static __device__ __forceinline__ unsigned short bf16rne(float x) {
  union { float f; unsigned u; } c; c.f = x;
  unsigned r = c.u + 0x7FFFu + ((c.u >> 16) & 1u);
  return (unsigned short)(r >> 16);
}

// ---------------- Kernel 1: Wh/e-factors (blocks 0..511) + adj masks (512..1535) ----------------
// (unchanged from R10 — verified)
__global__ __launch_bounds__(256, 2) void k_pre(
    const float* __restrict__ adj, const float* __restrict__ h,
    const float* __restrict__ W, const float* __restrict__ a,
    unsigned long long* __restrict__ adjq, unsigned short* __restrict__ whswz,
    float2* __restrict__ e1pn, unsigned* __restrict__ e2pk) {
  const int t = threadIdx.x, lane = t & 63, w = t >> 6;

  if (blockIdx.x >= 512) {
    const int bid = blockIdx.x - 512;
    const int row = bid * 2 + (w >> 1);
    const int half = w & 1;
    const float* ar = adj + (size_t)row * NN + half * 1024;
    unsigned long long* aq = adjq + row * 32 + half * 16;
    #pragma unroll
    for (int it = 0; it < 16; ++it) {
      unsigned long long m = __ballot(ar[it * 64 + lane] > 0.f);
      if (lane == 0) aq[it] = m;
    }
    return;
  }

  __shared__ __align__(16) float hs[32][68];
  const int rowBase = blockIdx.x * 32;
  const int b = rowBase >> 11, n0 = rowBase & (NN - 1);

  float wr[64];
  #pragma unroll
  for (int k = 0; k < 16; ++k)
    *(f4v*)&wr[k * 4] = *(const f4v*)&W[lane * 64 + k * 4];

  #pragma unroll
  for (int qq = 0; qq < 2; ++qq) {
    const int idx = t + 256 * qq;
    const int r = idx >> 4, c = (idx & 15) * 4;
    *(f4v*)&hs[r][c] = *(const f4v*)&h[(size_t)(rowBase + r) * 64 + c];
  }
  const float a1v = a[lane], a2v = a[64 + lane];
  __syncthreads();

  const int r0 = w * 8;
  float acc[8];
  #pragma unroll
  for (int rr = 0; rr < 8; ++rr) acc[rr] = 0.f;
  #pragma unroll
  for (int f4i = 0; f4i < 16; ++f4i) {
    f4v hv[8];
    #pragma unroll
    for (int rr = 0; rr < 8; ++rr)
      hv[rr] = *(const f4v*)&hs[r0 + rr][f4i * 4];
    #pragma unroll
    for (int x = 0; x < 4; ++x) {
      const float wv = wr[f4i * 4 + x];
      #pragma unroll
      for (int rr = 0; rr < 8; ++rr) acc[rr] = fmaf(hv[rr][x], wv, acc[rr]);
    }
  }

  {  // 32x32 B-frag swizzle store: [b][jc][oh][lane'][8]
    union { s8v v; unsigned u[4]; } cv;
    cv.u[0] = pk_bf16(acc[0], acc[1]);
    cv.u[1] = pk_bf16(acc[2], acc[3]);
    cv.u[2] = pk_bf16(acc[4], acc[5]);
    cv.u[3] = pk_bf16(acc[6], acc[7]);
    const int jc = (n0 + w * 8) >> 4;
    const int oh = lane >> 5;
    const int lp = ((w & 1) << 5) + (lane & 31);
    unsigned short* dst = whswz + ((size_t)b << 17) + (jc << 10) + (oh << 9) + (lp << 3);
    *(s8v*)dst = cv.v;
  }

  float s1[8], s2[8];
  #pragma unroll
  for (int rr = 0; rr < 8; ++rr) { s1[rr] = acc[rr] * a1v; s2[rr] = acc[rr] * a2v; }
  #pragma unroll
  for (int m = 1; m < 64; m <<= 1)
    #pragma unroll
    for (int rr = 0; rr < 8; ++rr) {
      s1[rr] += __shfl_xor(s1[rr], m);
      s2[rr] += __shfl_xor(s2[rr], m);
    }
  #pragma unroll
  for (int rr = 0; rr < 8; ++rr) {
    if (lane == 0) {
      e1pn[rowBase + rr + r0] = float2{__expf(s1[rr]), __expf(0.2f * s1[rr])};
      e2pk[rowBase + rr + r0] =
          (unsigned)bf16rne(__expf(s2[rr])) |
          ((unsigned)bf16rne(__expf(0.2f * s2[rr])) << 16);
    }
  }
}

// ---------------- Kernel 2: fused attention, deep-pipeline low-occupancy ----------------
// 512 blocks x 256 thr (4 waves; 2 blocks/CU). b=g&7 (XCD-pinned), 32 i-rows.
// Wave w = j-quarter: 32 chunks of 16 j; 4-chunk rolling register prefetch.
__global__ __launch_bounds__(256, 2) void k_attn(
    const unsigned long long* __restrict__ adjq,
    const unsigned short* __restrict__ whswz,
    const float2* __restrict__ e1png, const unsigned* __restrict__ e2pkg,
    float* __restrict__ out) {
  union SM {
    unsigned e2bf[NN];          //  8 KB packed {E2p,E2n} bf16 per j
    float pc[4][32][68];        // 34.8 KB partial C (aliased after loop)
  };
  __shared__ __align__(16) SM sm;
  __shared__ float ls[4][32];

  const int t = threadIdx.x, lane = t & 63, w = t >> 6;
  const int m32 = lane & 31, kh = lane >> 5;
  const int g = blockIdx.x;
  const int b = g & 7;
  const int i0 = (g >> 3) << 5;
  const size_t bN = (size_t)b * NN;

  // stage packed e2 factors (2048 dwords, 2 u4v per thread)
  ((u4v*)sm.e2bf)[t] = ((const u4v*)(e2pkg + bN))[t];
  ((u4v*)sm.e2bf)[t + 256] = ((const u4v*)(e2pkg + bN))[t + 256];

  const float2 e1f = e1png[bN + i0 + m32];
  const float E1p = e1f.x, E1n = e1f.y;

  // this lane's adj words for its i-row, this wave's j-quarter (8 u64)
  const unsigned long long* arow = adjq + (size_t)(i0 + m32) * 32 + w * 8;
  unsigned long long am[8];
  #pragma unroll
  for (int qq = 0; qq < 4; ++qq)
    *(u64v2*)&am[qq * 2] = *(const u64v2*)(arow + qq * 2);

  // B-frag base for this wave's chunks jc = w*32 + k
  const unsigned short* wb = whswz + ((size_t)b << 17) + ((size_t)(w * 32) << 10);

  f16v acc0, acc1;
  #pragma unroll
  for (int r = 0; r < 16; ++r) { acc0[r] = 0.f; acc1[r] = 0.f; }
  float psA = 0.f, psB = 0.f;

  // rolling prefetch: depth 4 chunks = 8 dwordx4 in flight (fits 256-VGPR cap)
  s8v buf[4][2];
  #pragma unroll
  for (int k = 0; k < 4; ++k) {
    buf[k][0] = *(const s8v*)(wb + (k << 10) + (lane << 3));
    buf[k][1] = *(const s8v*)(wb + (k << 10) + 512 + (lane << 3));
  }

  __syncthreads();   // e2bf staged

  #pragma unroll 4
  for (int k = 0; k < 32; ++k) {
    const int x = k & 3;                         // static under unroll-4
    // ---- P-gen for chunk k (LDS + registers only) ----
    const int eb = ((w * 32 + k) << 4) + (kh << 3);
    const u4v e0 = *(const u4v*)&sm.e2bf[eb];
    const u4v e1 = *(const u4v*)&sm.e2bf[eb + 4];
    const unsigned bits = (unsigned)(am[k >> 2] >> ((k & 3) * 16 + kh * 8)) & 0xffu;
    float p[8];
    #pragma unroll
    for (int e = 0; e < 8; ++e) {
      const unsigned dw = e < 4 ? e0[e] : e1[e - 4];
      const float E2p = __uint_as_float(dw << 16);
      const float E2n = __uint_as_float(dw & 0xffff0000u);
      const float mp = E1p * E2p;                // exp(e1+e2)
      const float mn = E1n * E2n;                // exp(0.2*(e1+e2))
      float pv = mp > 1.f ? mp : mn;             // leaky-relu in exp domain
      pv = ((bits >> e) & 1u) ? pv : 0.f;
      p[e] = pv;
    }
    // tree-sum into rotating accumulators (breaks serial fadd chain)
    {
      const float s01 = p[0] + p[1], s23 = p[2] + p[3];
      const float s45 = p[4] + p[5], s67 = p[6] + p[7];
      if (k & 1) psB += (s01 + s23) + (s45 + s67);
      else       psA += (s01 + s23) + (s45 + s67);
    }
    s8v af;
    {
      union { s8v v; unsigned u[4]; } cv;
      cv.u[0] = pk_bf16(p[0], p[1]);
      cv.u[1] = pk_bf16(p[2], p[3]);
      cv.u[2] = pk_bf16(p[4], p[5]);
      cv.u[3] = pk_bf16(p[6], p[7]);
      af = cv.v;
    }

    // ---- MFMA consumes buffered chunk ----
    acc0 = __builtin_amdgcn_mfma_f32_32x32x16_bf16(af, buf[x][0], acc0, 0, 0, 0);
    acc1 = __builtin_amdgcn_mfma_f32_32x32x16_bf16(af, buf[x][1], acc1, 0, 0, 0);

    // ---- refill slot with chunk k+4 ----
    if (k < 28) {
      buf[x][0] = *(const s8v*)(wb + ((k + 4) << 10) + (lane << 3));
      buf[x][1] = *(const s8v*)(wb + ((k + 4) << 10) + 512 + (lane << 3));
    }
  }

  // rowsum merge across k-halves
  float psum = psA + psB;
  psum += __shfl_xor(psum, 32);
  __syncthreads();              // all e2bf reads done -> pc alias safe
  if (lane < 32) ls[w][lane] = psum;
  // publish partial C (C/D 32x32 layout: col=lane&31, row=(r&3)+8*(r>>2)+4*kh)
  #pragma unroll
  for (int r = 0; r < 16; ++r) {
    const int row = (r & 3) + 8 * (r >> 2) + 4 * kh;
    sm.pc[w][row][m32] = acc0[r];
    sm.pc[w][row][32 + m32] = acc1[r];
  }
  __syncthreads();

  // gather across 4 waves: thread t -> row t>>3, 8 cols at (t&7)*8
  const int row = t >> 3, c0 = (t & 7) * 8;
  f4v s0 = *(const f4v*)&sm.pc[0][row][c0];
  f4v s1 = *(const f4v*)&sm.pc[0][row][c0 + 4];
  #pragma unroll
  for (int j = 1; j < 4; ++j) {
    s0 += *(const f4v*)&sm.pc[j][row][c0];
    s1 += *(const f4v*)&sm.pc[j][row][c0 + 4];
  }
  const float rsum = ls[0][row] + ls[1][row] + ls[2][row] + ls[3][row];
  f4v o0, o1;
  #pragma unroll
  for (int xx = 0; xx < 4; ++xx) {
    float v = s0[xx] / rsum;
    o0[xx] = v > 0.f ? v : expm1f(v);
    v = s1[xx] / rsum;
    o1[xx] = v > 0.f ? v : expm1f(v);
  }
  float* op = &out[(bN + i0 + row) * 64 + c0];
  *(f4v*)op = o0;
  *(f4v*)(op + 4) = o1;
}

extern "C" void kernel_launch(void* const* d_in, const int* in_sizes, int n_in,
                              void* d_out, int out_size, void* d_ws, size_t ws_size,
                              hipStream_t stream) {
  (void)in_sizes; (void)n_in; (void)out_size; (void)ws_size;
  const float* h   = (const float*)d_in[0];
  const float* adj = (const float*)d_in[1];
  const float* W   = (const float*)d_in[2];
  const float* a   = (const float*)d_in[3];
  float* outp = (float*)d_out;

  // ws carve: whswz 2 MB | e1pn 128 KB | e2pk 64 KB | adjq 512 KB
  unsigned short* whswz = (unsigned short*)d_ws;
  float2* e1pn = (float2*)((char*)d_ws + (size_t)BB * 64 * NN * 2);
  unsigned* e2pk = (unsigned*)(e1pn + (size_t)BB * NN);
  unsigned long long* adjq = (unsigned long long*)(e2pk + (size_t)BB * NN);

  k_pre<<<1536, 256, 0, stream>>>(adj, h, W, a, adjq, whswz, e1pn, e2pk);
  k_attn<<<512, 256, 0, stream>>>(adjq, whswz, e1pn, e2pk, outp);
}